// Round 1
// baseline (1050.809 us; speedup 1.0000x reference)
//
#include <hip/hip_runtime.h>

#define FIN 128
#define FH 50

__global__ void deg_kernel(const int* __restrict__ dst, int E, float* __restrict__ deg) {
    int e = blockIdx.x * blockDim.x + threadIdx.x;
    if (e < E) atomicAdd(&deg[dst[e]], 1.0f);
}

__global__ void dinv_kernel(const float* __restrict__ deg, float* __restrict__ dinv, int n) {
    int i = blockIdx.x * blockDim.x + threadIdx.x;
    if (i < n) dinv[i] = rsqrtf(deg[i] + 1.0f);  // +1 = self-loop
}

// hs[row] = (x[row] @ W1) * dinv[row]; also init acc (=d_out) with same value
// (self-loop contribution to the scatter sum).
__global__ __launch_bounds__(256) void gemm1_kernel(
    const float* __restrict__ x, const float* __restrict__ W,
    const float* __restrict__ dinv,
    float* __restrict__ hs, float* __restrict__ acc, int n) {
    __shared__ float Ws[FIN * FH];
    for (int i = threadIdx.x; i < FIN * FH; i += 256) Ws[i] = W[i];
    __syncthreads();
    int row = blockIdx.x * 256 + threadIdx.x;
    if (row >= n) return;
    float a[FH];
#pragma unroll
    for (int c = 0; c < FH; c++) a[c] = 0.f;
    const float4* xr = (const float4*)(x + (size_t)row * FIN);
    for (int k4 = 0; k4 < FIN / 4; k4++) {
        float4 xv = xr[k4];
        const float* w0 = &Ws[k4 * 4 * FH];
#pragma unroll
        for (int c = 0; c < FH; c++) {
            a[c] = fmaf(xv.x, w0[c], a[c]);
            a[c] = fmaf(xv.y, w0[c + FH], a[c]);
            a[c] = fmaf(xv.z, w0[c + 2 * FH], a[c]);
            a[c] = fmaf(xv.w, w0[c + 3 * FH], a[c]);
        }
    }
    float dv = dinv[row];
    float* hp = hs + (size_t)row * FH;
    float* ap = acc + (size_t)row * FH;
#pragma unroll
    for (int c = 0; c < FH; c++) { float v = a[c] * dv; hp[c] = v; ap[c] = v; }
}

// acc[dst*50+f] += hs[src*50+f] for all (edge, f)
__global__ void scatter_kernel(const float* __restrict__ hs,
                               const int* __restrict__ src, const int* __restrict__ dst,
                               float* acc, long long total) {
    long long tid = (long long)blockIdx.x * blockDim.x + threadIdx.x;
    if (tid >= total) return;
    int e = (int)(tid / FH);
    int f = (int)(tid - (long long)e * FH);
    int s = src[e], d = dst[e];
    atomicAdd(&acc[(size_t)d * FH + f], hs[(size_t)s * FH + f]);
}

// io = relu(dinv[i]*io + b[f])
__global__ void bias_relu_kernel(float* __restrict__ io, const float* __restrict__ dinv,
                                 const float* __restrict__ b, long long total) {
    long long tid = (long long)blockIdx.x * blockDim.x + threadIdx.x;
    if (tid >= total) return;
    int i = (int)(tid / FH);
    int f = (int)(tid - (long long)i * FH);
    float v = fmaf(dinv[i], io[tid], b[f]);
    io[tid] = fmaxf(v, 0.f);
}

// hs[row] = (io[row] @ W2) * dinv[row]; then io[row] = hs[row] (scatter init).
// io aliases d_out: each thread reads its whole row into regs before writing.
__global__ __launch_bounds__(256) void gemm2_kernel(
    const float* __restrict__ W, const float* __restrict__ dinv,
    float* __restrict__ hs, float* io, int n) {
    __shared__ float Ws[FH * FH];
    for (int i = threadIdx.x; i < FH * FH; i += 256) Ws[i] = W[i];
    __syncthreads();
    int row = blockIdx.x * 256 + threadIdx.x;
    if (row >= n) return;
    float xr[FH];
    float* iop = io + (size_t)row * FH;
#pragma unroll
    for (int k = 0; k < FH; k++) xr[k] = iop[k];
    float a[FH];
#pragma unroll
    for (int c = 0; c < FH; c++) a[c] = 0.f;
    for (int k = 0; k < FH; k++) {
        float xv = xr[k];
        const float* w = &Ws[k * FH];
#pragma unroll
        for (int c = 0; c < FH; c++) a[c] = fmaf(xv, w[c], a[c]);
    }
    float dv = dinv[row];
    float* hp = hs + (size_t)row * FH;
#pragma unroll
    for (int c = 0; c < FH; c++) { float v = a[c] * dv; hp[c] = v; iop[c] = v; }
}

// out = dinv[i]*out + b[f]
__global__ void final_kernel(float* __restrict__ io, const float* __restrict__ dinv,
                             const float* __restrict__ b, long long total) {
    long long tid = (long long)blockIdx.x * blockDim.x + threadIdx.x;
    if (tid >= total) return;
    int i = (int)(tid / FH);
    int f = (int)(tid - (long long)i * FH);
    io[tid] = fmaf(dinv[i], io[tid], b[f]);
}

extern "C" void kernel_launch(void* const* d_in, const int* in_sizes, int n_in,
                              void* d_out, int out_size, void* d_ws, size_t ws_size,
                              hipStream_t stream) {
    const float* x  = (const float*)d_in[0];
    const float* W1 = (const float*)d_in[1];
    const float* b1 = (const float*)d_in[2];
    const float* W2 = (const float*)d_in[3];
    const float* b2 = (const float*)d_in[4];
    const int*   ei = (const int*)d_in[5];

    int n = in_sizes[0] / FIN;       // 100000
    int E = in_sizes[5] / 2;         // 1600000
    const int* src = ei;
    const int* dst = ei + E;

    char* ws = (char*)d_ws;
    size_t nbytes_aligned = (((size_t)n * 4) + 511) & ~(size_t)511;
    float* dinv = (float*)ws;
    float* deg  = (float*)(ws + nbytes_aligned);
    float* hs   = (float*)(ws + 2 * nbytes_aligned);   // n*50 floats
    float* out  = (float*)d_out;

    hipMemsetAsync(deg, 0, (size_t)n * 4, stream);

    deg_kernel<<<(E + 255) / 256, 256, 0, stream>>>(dst, E, deg);
    dinv_kernel<<<(n + 255) / 256, 256, 0, stream>>>(deg, dinv, n);

    int rowBlocks = (n + 255) / 256;
    gemm1_kernel<<<rowBlocks, 256, 0, stream>>>(x, W1, dinv, hs, out, n);

    long long tot  = (long long)E * FH;
    long long ntot = (long long)n * FH;
    int scatBlocks = (int)((tot + 255) / 256);
    int nBlocks    = (int)((ntot + 255) / 256);

    scatter_kernel<<<scatBlocks, 256, 0, stream>>>(hs, src, dst, out, tot);
    bias_relu_kernel<<<nBlocks, 256, 0, stream>>>(out, dinv, b1, ntot);
    gemm2_kernel<<<rowBlocks, 256, 0, stream>>>(W2, dinv, hs, out, n);
    scatter_kernel<<<scatBlocks, 256, 0, stream>>>(hs, src, dst, out, tot);
    final_kernel<<<nBlocks, 256, 0, stream>>>(out, dinv, b2, ntot);
}

// Round 2
// 580.334 us; speedup vs baseline: 1.8107x; 1.8107x over previous
//
#include <hip/hip_runtime.h>

#define FIN 128
#define FH 50
#define HSTRIDE 64
#define SCAN_B 256

__global__ void deg_kernel(const int* __restrict__ dst, int E, int* __restrict__ deg) {
    int e = blockIdx.x * blockDim.x + threadIdx.x;
    if (e < E) atomicAdd(&deg[dst[e]], 1);
}

// per-chunk exclusive scan -> excl (stored in rowptr), chunk totals -> bsum
__global__ __launch_bounds__(SCAN_B) void scan1_kernel(const int* __restrict__ deg,
                                                       int* __restrict__ excl,
                                                       int* __restrict__ bsum, int n) {
    __shared__ int tmp[SCAN_B];
    int t = threadIdx.x;
    int i = blockIdx.x * SCAN_B + t;
    int v = (i < n) ? deg[i] : 0;
    tmp[t] = v;
    __syncthreads();
    for (int off = 1; off < SCAN_B; off <<= 1) {
        int add = (t >= off) ? tmp[t - off] : 0;
        __syncthreads();
        tmp[t] += add;
        __syncthreads();
    }
    if (i < n) excl[i] = tmp[t] - v;
    if (t == SCAN_B - 1) bsum[blockIdx.x] = tmp[t];
}

// exclusive scan of block sums (nb <= 512), in place
__global__ __launch_bounds__(512) void scan2_kernel(int* __restrict__ bsum, int nb) {
    __shared__ int tmp[512];
    int t = threadIdx.x;
    int v = (t < nb) ? bsum[t] : 0;
    tmp[t] = v;
    __syncthreads();
    for (int off = 1; off < 512; off <<= 1) {
        int add = (t >= off) ? tmp[t - off] : 0;
        __syncthreads();
        tmp[t] += add;
        __syncthreads();
    }
    if (t < nb) bsum[t] = tmp[t] - v;
}

__global__ __launch_bounds__(SCAN_B) void scan3_kernel(const int* __restrict__ deg,
                                                       int* __restrict__ rowptr,
                                                       int* __restrict__ cursor,
                                                       float* __restrict__ dinv,
                                                       const int* __restrict__ bsum,
                                                       int n, int E) {
    int i = blockIdx.x * SCAN_B + threadIdx.x;
    if (i < n) {
        int r = rowptr[i] + bsum[blockIdx.x];
        rowptr[i] = r;
        cursor[i] = r;
        dinv[i] = rsqrtf((float)deg[i] + 1.0f);  // +1 = self-loop
    }
    if (i == 0) rowptr[n] = E;
}

__global__ void fill_kernel(const int* __restrict__ src, const int* __restrict__ dst,
                            int* __restrict__ cursor, int* __restrict__ csr, int E) {
    int e = blockIdx.x * blockDim.x + threadIdx.x;
    if (e < E) {
        int pos = atomicAdd(&cursor[dst[e]], 1);
        csr[pos] = src[e];
    }
}

// hs[row] = (x[row] @ W1) * dinv[row], padded stride 64, pad zeroed
__global__ __launch_bounds__(256) void gemm1_kernel(
    const float* __restrict__ x, const float* __restrict__ W,
    const float* __restrict__ dinv, float* __restrict__ hs, int n) {
    __shared__ float Ws[FIN * FH];
    for (int i = threadIdx.x; i < FIN * FH; i += 256) Ws[i] = W[i];
    __syncthreads();
    int row = blockIdx.x * 256 + threadIdx.x;
    if (row >= n) return;
    float a[FH];
#pragma unroll
    for (int c = 0; c < FH; c++) a[c] = 0.f;
    const float4* xr = (const float4*)(x + (size_t)row * FIN);
    for (int k4 = 0; k4 < FIN / 4; k4++) {
        float4 xv = xr[k4];
        const float* w0 = &Ws[k4 * 4 * FH];
#pragma unroll
        for (int c = 0; c < FH; c++) {
            a[c] = fmaf(xv.x, w0[c], a[c]);
            a[c] = fmaf(xv.y, w0[c + FH], a[c]);
            a[c] = fmaf(xv.z, w0[c + 2 * FH], a[c]);
            a[c] = fmaf(xv.w, w0[c + 3 * FH], a[c]);
        }
    }
    float dv = dinv[row];
    float* hp = hs + ((size_t)row << 6);
#pragma unroll
    for (int c = 0; c < FH; c++) hp[c] = a[c] * dv;
#pragma unroll
    for (int c = FH; c < HSTRIDE; c++) hp[c] = 0.f;
}

// hs[row] = (h1[row] @ W2) * dinv[row]; h1 = d_out from gather1
__global__ __launch_bounds__(256) void gemm2_kernel(
    const float* __restrict__ h1, const float* __restrict__ W,
    const float* __restrict__ dinv, float* __restrict__ hs, int n) {
    __shared__ float Ws[FH * FH];
    for (int i = threadIdx.x; i < FH * FH; i += 256) Ws[i] = W[i];
    __syncthreads();
    int row = blockIdx.x * 256 + threadIdx.x;
    if (row >= n) return;
    const float* xp = h1 + (size_t)row * FH;
    float xr[FH];
#pragma unroll
    for (int k = 0; k < FH; k++) xr[k] = xp[k];
    float a[FH];
#pragma unroll
    for (int c = 0; c < FH; c++) a[c] = 0.f;
    for (int k = 0; k < FH; k++) {
        float xv = xr[k];
        const float* w = &Ws[k * FH];
#pragma unroll
        for (int c = 0; c < FH; c++) a[c] = fmaf(xv, w[c], a[c]);
    }
    float dv = dinv[row];
    float* hp = hs + ((size_t)row << 6);
#pragma unroll
    for (int c = 0; c < FH; c++) hp[c] = a[c] * dv;
#pragma unroll
    for (int c = FH; c < HSTRIDE; c++) hp[c] = 0.f;
}

// one wave per dst row: acc = hs[self] + sum over in-edges hs[src];
// out = relu?(dinv*acc + b)
__global__ __launch_bounds__(256) void gather_kernel(
    const float* __restrict__ hs, const int* __restrict__ rowptr,
    const int* __restrict__ csr, const float* __restrict__ dinv,
    const float* __restrict__ b, float* __restrict__ out, int n, int do_relu) {
    int wid = blockIdx.x * 4 + (threadIdx.x >> 6);
    int lane = threadIdx.x & 63;
    if (wid >= n) return;
    int beg = rowptr[wid];
    int end = rowptr[wid + 1];
    float acc = hs[((size_t)wid << 6) + lane];  // self-loop term (pad lanes read 0)
    for (int base = beg; base < end; base += 64) {
        int rem = end - base;
        int idx = (lane < rem) ? csr[base + lane] : 0;
        int cnt = rem < 64 ? rem : 64;
        for (int j = 0; j < cnt; j++) {
            int s = __shfl(idx, j);
            acc += hs[((size_t)s << 6) + lane];
        }
    }
    if (lane < FH) {
        float v = fmaf(dinv[wid], acc, b[lane]);
        if (do_relu) v = fmaxf(v, 0.f);
        out[(size_t)wid * FH + lane] = v;
    }
}

extern "C" void kernel_launch(void* const* d_in, const int* in_sizes, int n_in,
                              void* d_out, int out_size, void* d_ws, size_t ws_size,
                              hipStream_t stream) {
    const float* x  = (const float*)d_in[0];
    const float* W1 = (const float*)d_in[1];
    const float* b1 = (const float*)d_in[2];
    const float* W2 = (const float*)d_in[3];
    const float* b2 = (const float*)d_in[4];
    const int*   ei = (const int*)d_in[5];

    int n = in_sizes[0] / FIN;   // 100000
    int E = in_sizes[5] / 2;     // 1600000
    const int* src = ei;
    const int* dst = ei + E;

    char* ws = (char*)d_ws;
    size_t off = 0;
    auto alloc = [&](size_t bytes) {
        void* p = ws + off;
        off = (off + bytes + 511) & ~(size_t)511;
        return p;
    };
    int*   deg    = (int*)alloc((size_t)n * 4);
    int*   rowptr = (int*)alloc((size_t)(n + 1) * 4);
    int*   cursor = (int*)alloc((size_t)n * 4);
    int*   bsum   = (int*)alloc(1024 * 4);
    float* dinv   = (float*)alloc((size_t)n * 4);
    int*   csr    = (int*)alloc((size_t)E * 4);
    float* hs     = (float*)alloc((size_t)n * HSTRIDE * 4);
    float* out    = (float*)d_out;

    hipMemsetAsync(deg, 0, (size_t)n * 4, stream);

    int eBlocks = (E + 255) / 256;
    int nChunks = (n + SCAN_B - 1) / SCAN_B;  // 391 <= 512
    deg_kernel<<<eBlocks, 256, 0, stream>>>(dst, E, deg);
    scan1_kernel<<<nChunks, SCAN_B, 0, stream>>>(deg, rowptr, bsum, n);
    scan2_kernel<<<1, 512, 0, stream>>>(bsum, nChunks);
    scan3_kernel<<<nChunks, SCAN_B, 0, stream>>>(deg, rowptr, cursor, dinv, bsum, n, E);
    fill_kernel<<<eBlocks, 256, 0, stream>>>(src, dst, cursor, csr, E);

    int rowBlocks = (n + 255) / 256;
    int gatherBlocks = (n + 3) / 4;   // 4 waves/block, 1 wave/row

    gemm1_kernel<<<rowBlocks, 256, 0, stream>>>(x, W1, dinv, hs, n);
    gather_kernel<<<gatherBlocks, 256, 0, stream>>>(hs, rowptr, csr, dinv, b1, out, n, 1);
    gemm2_kernel<<<rowBlocks, 256, 0, stream>>>(out, W2, dinv, hs, n);
    gather_kernel<<<gatherBlocks, 256, 0, stream>>>(hs, rowptr, csr, dinv, b2, out, n, 0);
}

// Round 3
// 444.473 us; speedup vs baseline: 2.3642x; 1.3057x over previous
//
#include <hip/hip_runtime.h>

#define FIN 128
#define FH 50
#define HSTRIDE 64
#define MAXNB 1024        // supports n <= 131072 with 128-node buckets
#define BSHIFT 7
#define BSIZE 128
#define PCHUNK 8192       // edges per partition workgroup
#define SRCMASK 0x01FFFFFFu

// -------- CSR build: bucketed two-level counting sort --------

// per-WG LDS histogram of dst buckets -> global bhist
__global__ __launch_bounds__(256) void bhist_kernel(const int* __restrict__ dst, int E,
                                                    int* __restrict__ bhist, int NB) {
    __shared__ int h[MAXNB];
    int t = threadIdx.x;
    for (int i = t; i < NB; i += 256) h[i] = 0;
    __syncthreads();
    for (int e = blockIdx.x * 256 + t; e < E; e += gridDim.x * 256)
        atomicAdd(&h[dst[e] >> BSHIFT], 1);
    __syncthreads();
    for (int i = t; i < NB; i += 256) { int c = h[i]; if (c) atomicAdd(&bhist[i], c); }
}

// exclusive scan of bucket counts (NB <= 1024); also init gcursor, rowptr[n]
__global__ __launch_bounds__(1024) void bscan_kernel(const int* __restrict__ bhist,
                                                     int* __restrict__ bofs,
                                                     int* __restrict__ gcursor,
                                                     int* __restrict__ rowptr,
                                                     int NB, int n, int E) {
    __shared__ int tmp[1024];
    int t = threadIdx.x;
    int v = (t < NB) ? bhist[t] : 0;
    tmp[t] = v;
    __syncthreads();
    for (int off = 1; off < 1024; off <<= 1) {
        int add = (t >= off) ? tmp[t - off] : 0;
        __syncthreads();
        tmp[t] += add;
        __syncthreads();
    }
    if (t < NB) { int e = tmp[t] - v; bofs[t] = e; gcursor[t] = e; }
    if (t == 0) { bofs[NB] = E; rowptr[n] = E; }
}

// partition edges into bucket-contiguous 'packed' array: word = (dlocal<<25)|src
__global__ __launch_bounds__(256) void partition_kernel(const int* __restrict__ src,
                                                        const int* __restrict__ dst,
                                                        int* __restrict__ gcursor,
                                                        unsigned int* __restrict__ packed,
                                                        int E, int NB) {
    __shared__ int hist[MAXNB];   // phase1: counts; phase3: local cursor
    __shared__ int wbase[MAXNB];
    int t = threadIdx.x;
    int base = blockIdx.x * PCHUNK;
    for (int i = t; i < NB; i += 256) hist[i] = 0;
    __syncthreads();
#pragma unroll 4
    for (int i = 0; i < PCHUNK / 256; i++) {
        int e = base + t + i * 256;
        if (e < E) atomicAdd(&hist[dst[e] >> BSHIFT], 1);
    }
    __syncthreads();
    for (int i = t; i < NB; i += 256) {
        int c = hist[i];
        wbase[i] = c ? atomicAdd(&gcursor[i], c) : 0;
        hist[i] = 0;   // becomes local cursor
    }
    __syncthreads();
#pragma unroll 4
    for (int i = 0; i < PCHUNK / 256; i++) {
        int e = base + t + i * 256;
        if (e < E) {
            unsigned int s = (unsigned int)src[e];
            int d = dst[e];
            int b = d >> BSHIFT;
            int off = atomicAdd(&hist[b], 1);
            packed[wbase[b] + off] = ((unsigned int)(d & (BSIZE - 1)) << 25) | s;
        }
    }
}

// one WG per bucket: local degree hist -> scan -> rowptr/dinv -> csr fill
__global__ __launch_bounds__(256) void bucket_build_kernel(const unsigned int* __restrict__ packed,
                                                           const int* __restrict__ bofs,
                                                           int* __restrict__ rowptr,
                                                           float* __restrict__ dinv,
                                                           int* __restrict__ csr, int n) {
    __shared__ int degl[BSIZE];
    __shared__ int excl[BSIZE];
    __shared__ int lcur[BSIZE];
    int b = blockIdx.x;
    int t = threadIdx.x;
    int nbeg = b << BSHIFT;
    int ebeg = bofs[b], eend = bofs[b + 1];
    if (t < BSIZE) degl[t] = 0;
    __syncthreads();
    for (int e = ebeg + t; e < eend; e += 256)
        atomicAdd(&degl[packed[e] >> 25], 1);
    __syncthreads();
    int v = (t < BSIZE) ? degl[t] : 0;
    if (t < BSIZE) excl[t] = v;
    __syncthreads();
    for (int off = 1; off < BSIZE; off <<= 1) {
        int add = (t >= off && t < BSIZE) ? excl[t - off] : 0;
        __syncthreads();
        if (t < BSIZE) excl[t] += add;
        __syncthreads();
    }
    if (t < BSIZE) {
        int ex = excl[t] - v;
        int node = nbeg + t;
        if (node < n) {
            rowptr[node] = ebeg + ex;
            dinv[node] = rsqrtf((float)v + 1.0f);  // +1 = self-loop
        }
        lcur[t] = ex;
    }
    __syncthreads();
    for (int e = ebeg + t; e < eend; e += 256) {
        unsigned int w = packed[e];
        int off = atomicAdd(&lcur[w >> 25], 1);
        csr[ebeg + off] = (int)(w & SRCMASK);
    }
}

// -------- dense compute --------

// hs[row] = (x[row] @ W1) * dinv[row], padded stride 64, pad zeroed
__global__ __launch_bounds__(256) void gemm1_kernel(
    const float* __restrict__ x, const float* __restrict__ W,
    const float* __restrict__ dinv, float* __restrict__ hs, int n) {
    __shared__ float Ws[FIN * FH];
    for (int i = threadIdx.x; i < FIN * FH; i += 256) Ws[i] = W[i];
    __syncthreads();
    int row = blockIdx.x * 256 + threadIdx.x;
    if (row >= n) return;
    float a[FH];
#pragma unroll
    for (int c = 0; c < FH; c++) a[c] = 0.f;
    const float4* xr = (const float4*)(x + (size_t)row * FIN);
    for (int k4 = 0; k4 < FIN / 4; k4++) {
        float4 xv = xr[k4];
        const float* w0 = &Ws[k4 * 4 * FH];
#pragma unroll
        for (int c = 0; c < FH; c++) {
            a[c] = fmaf(xv.x, w0[c], a[c]);
            a[c] = fmaf(xv.y, w0[c + FH], a[c]);
            a[c] = fmaf(xv.z, w0[c + 2 * FH], a[c]);
            a[c] = fmaf(xv.w, w0[c + 3 * FH], a[c]);
        }
    }
    float dv = dinv[row];
    float* hp = hs + ((size_t)row << 6);
#pragma unroll
    for (int c = 0; c < FH; c++) hp[c] = a[c] * dv;
#pragma unroll
    for (int c = FH; c < HSTRIDE; c++) hp[c] = 0.f;
}

// hs[row] = (h1[row] @ W2) * dinv[row]
__global__ __launch_bounds__(256) void gemm2_kernel(
    const float* __restrict__ h1, const float* __restrict__ W,
    const float* __restrict__ dinv, float* __restrict__ hs, int n) {
    __shared__ float Ws[FH * FH];
    for (int i = threadIdx.x; i < FH * FH; i += 256) Ws[i] = W[i];
    __syncthreads();
    int row = blockIdx.x * 256 + threadIdx.x;
    if (row >= n) return;
    const float* xp = h1 + (size_t)row * FH;
    float xr[FH];
#pragma unroll
    for (int k = 0; k < FH; k++) xr[k] = xp[k];
    float a[FH];
#pragma unroll
    for (int c = 0; c < FH; c++) a[c] = 0.f;
    for (int k = 0; k < FH; k++) {
        float xv = xr[k];
        const float* w = &Ws[k * FH];
#pragma unroll
        for (int c = 0; c < FH; c++) a[c] = fmaf(xv, w[c], a[c]);
    }
    float dv = dinv[row];
    float* hp = hs + ((size_t)row << 6);
#pragma unroll
    for (int c = 0; c < FH; c++) hp[c] = a[c] * dv;
#pragma unroll
    for (int c = FH; c < HSTRIDE; c++) hp[c] = 0.f;
}

// one wave per dst row: acc = hs[self] + sum over in-edges hs[src];
// out = relu?(dinv*acc + b)
__global__ __launch_bounds__(256) void gather_kernel(
    const float* __restrict__ hs, const int* __restrict__ rowptr,
    const int* __restrict__ csr, const float* __restrict__ dinv,
    const float* __restrict__ b, float* __restrict__ out, int n, int do_relu) {
    int wid = blockIdx.x * 4 + (threadIdx.x >> 6);
    int lane = threadIdx.x & 63;
    if (wid >= n) return;
    int beg = rowptr[wid];
    int end = rowptr[wid + 1];
    float acc = hs[((size_t)wid << 6) + lane];  // self-loop term (pad lanes read 0)
    for (int base = beg; base < end; base += 64) {
        int rem = end - base;
        int idx = (lane < rem) ? csr[base + lane] : 0;
        int cnt = rem < 64 ? rem : 64;
        for (int j = 0; j < cnt; j++) {
            int s = __shfl(idx, j);
            acc += hs[((size_t)s << 6) + lane];
        }
    }
    if (lane < FH) {
        float v = fmaf(dinv[wid], acc, b[lane]);
        if (do_relu) v = fmaxf(v, 0.f);
        out[(size_t)wid * FH + lane] = v;
    }
}

extern "C" void kernel_launch(void* const* d_in, const int* in_sizes, int n_in,
                              void* d_out, int out_size, void* d_ws, size_t ws_size,
                              hipStream_t stream) {
    const float* x  = (const float*)d_in[0];
    const float* W1 = (const float*)d_in[1];
    const float* b1 = (const float*)d_in[2];
    const float* W2 = (const float*)d_in[3];
    const float* b2 = (const float*)d_in[4];
    const int*   ei = (const int*)d_in[5];

    int n = in_sizes[0] / FIN;   // 100000
    int E = in_sizes[5] / 2;     // 1600000
    const int* src = ei;
    const int* dst = ei + E;
    int NB = (n + BSIZE - 1) >> BSHIFT;   // 782

    char* ws = (char*)d_ws;
    size_t off = 0;
    auto alloc = [&](size_t bytes) {
        void* p = ws + off;
        off = (off + bytes + 511) & ~(size_t)511;
        return p;
    };
    int*          bhist   = (int*)alloc((size_t)MAXNB * 4);
    int*          bofs    = (int*)alloc((size_t)(MAXNB + 1) * 4);
    int*          gcursor = (int*)alloc((size_t)MAXNB * 4);
    int*          rowptr  = (int*)alloc((size_t)(n + 1) * 4);
    float*        dinv    = (float*)alloc((size_t)n * 4);
    unsigned int* packed  = (unsigned int*)alloc((size_t)E * 4);
    int*          csr     = (int*)alloc((size_t)E * 4);
    float*        hs      = (float*)alloc((size_t)n * HSTRIDE * 4);
    float*        out     = (float*)d_out;

    hipMemsetAsync(bhist, 0, (size_t)NB * 4, stream);

    bhist_kernel<<<256, 256, 0, stream>>>(dst, E, bhist, NB);
    bscan_kernel<<<1, 1024, 0, stream>>>(bhist, bofs, gcursor, rowptr, NB, n, E);
    int pChunks = (E + PCHUNK - 1) / PCHUNK;   // 196
    partition_kernel<<<pChunks, 256, 0, stream>>>(src, dst, gcursor, packed, E, NB);
    bucket_build_kernel<<<NB, 256, 0, stream>>>(packed, bofs, rowptr, dinv, csr, n);

    int rowBlocks = (n + 255) / 256;
    int gatherBlocks = (n + 3) / 4;   // 4 waves/block, 1 wave/row

    gemm1_kernel<<<rowBlocks, 256, 0, stream>>>(x, W1, dinv, hs, n);
    gather_kernel<<<gatherBlocks, 256, 0, stream>>>(hs, rowptr, csr, dinv, b1, out, n, 1);
    gemm2_kernel<<<rowBlocks, 256, 0, stream>>>(out, W2, dinv, hs, n);
    gather_kernel<<<gatherBlocks, 256, 0, stream>>>(hs, rowptr, csr, dinv, b2, out, n, 0);
}

// Round 4
// 422.626 us; speedup vs baseline: 2.4864x; 1.0517x over previous
//
#include <hip/hip_runtime.h>
#include <hip/hip_fp16.h>

#define FIN 128
#define FH 50
#define HSTRIDE 64
#define MAXNB 1024        // supports n <= 131072 with 128-node buckets
#define BSHIFT 7
#define BSIZE 128
#define PCHUNK 8192       // edges per partition workgroup
#define SRCMASK 0x01FFFFFFu

// -------- CSR build: bucketed two-level counting sort --------

// per-WG LDS histogram of dst buckets -> global bhist
__global__ __launch_bounds__(256) void bhist_kernel(const int* __restrict__ dst, int E,
                                                    int* __restrict__ bhist, int NB) {
    __shared__ int h[MAXNB];
    int t = threadIdx.x;
    for (int i = t; i < NB; i += 256) h[i] = 0;
    __syncthreads();
    for (int e = blockIdx.x * 256 + t; e < E; e += gridDim.x * 256)
        atomicAdd(&h[dst[e] >> BSHIFT], 1);
    __syncthreads();
    for (int i = t; i < NB; i += 256) { int c = h[i]; if (c) atomicAdd(&bhist[i], c); }
}

// exclusive scan of bucket counts (NB <= 1024); also init gcursor, rowptr[n]
__global__ __launch_bounds__(1024) void bscan_kernel(const int* __restrict__ bhist,
                                                     int* __restrict__ bofs,
                                                     int* __restrict__ gcursor,
                                                     int* __restrict__ rowptr,
                                                     int NB, int n, int E) {
    __shared__ int tmp[1024];
    int t = threadIdx.x;
    int v = (t < NB) ? bhist[t] : 0;
    tmp[t] = v;
    __syncthreads();
    for (int off = 1; off < 1024; off <<= 1) {
        int add = (t >= off) ? tmp[t - off] : 0;
        __syncthreads();
        tmp[t] += add;
        __syncthreads();
    }
    if (t < NB) { int e = tmp[t] - v; bofs[t] = e; gcursor[t] = e; }
    if (t == 0) { bofs[NB] = E; rowptr[n] = E; }
}

// partition edges into bucket-contiguous 'packed' array: word = (dlocal<<25)|src
__global__ __launch_bounds__(256) void partition_kernel(const int* __restrict__ src,
                                                        const int* __restrict__ dst,
                                                        int* __restrict__ gcursor,
                                                        unsigned int* __restrict__ packed,
                                                        int E, int NB) {
    __shared__ int hist[MAXNB];   // phase1: counts; phase3: local cursor
    __shared__ int wbase[MAXNB];
    int t = threadIdx.x;
    int base = blockIdx.x * PCHUNK;
    for (int i = t; i < NB; i += 256) hist[i] = 0;
    __syncthreads();
#pragma unroll 4
    for (int i = 0; i < PCHUNK / 256; i++) {
        int e = base + t + i * 256;
        if (e < E) atomicAdd(&hist[dst[e] >> BSHIFT], 1);
    }
    __syncthreads();
    for (int i = t; i < NB; i += 256) {
        int c = hist[i];
        wbase[i] = c ? atomicAdd(&gcursor[i], c) : 0;
        hist[i] = 0;   // becomes local cursor
    }
    __syncthreads();
#pragma unroll 4
    for (int i = 0; i < PCHUNK / 256; i++) {
        int e = base + t + i * 256;
        if (e < E) {
            unsigned int s = (unsigned int)src[e];
            int d = dst[e];
            int b = d >> BSHIFT;
            int off = atomicAdd(&hist[b], 1);
            packed[wbase[b] + off] = ((unsigned int)(d & (BSIZE - 1)) << 25) | s;
        }
    }
}

// one WG per bucket: local degree hist -> scan -> rowptr/dinv -> csr fill
__global__ __launch_bounds__(256) void bucket_build_kernel(const unsigned int* __restrict__ packed,
                                                           const int* __restrict__ bofs,
                                                           int* __restrict__ rowptr,
                                                           float* __restrict__ dinv,
                                                           int* __restrict__ csr, int n) {
    __shared__ int degl[BSIZE];
    __shared__ int excl[BSIZE];
    __shared__ int lcur[BSIZE];
    int b = blockIdx.x;
    int t = threadIdx.x;
    int nbeg = b << BSHIFT;
    int ebeg = bofs[b], eend = bofs[b + 1];
    if (t < BSIZE) degl[t] = 0;
    __syncthreads();
    for (int e = ebeg + t; e < eend; e += 256)
        atomicAdd(&degl[packed[e] >> 25], 1);
    __syncthreads();
    int v = (t < BSIZE) ? degl[t] : 0;
    if (t < BSIZE) excl[t] = v;
    __syncthreads();
    for (int off = 1; off < BSIZE; off <<= 1) {
        int add = (t >= off && t < BSIZE) ? excl[t - off] : 0;
        __syncthreads();
        if (t < BSIZE) excl[t] += add;
        __syncthreads();
    }
    if (t < BSIZE) {
        int ex = excl[t] - v;
        int node = nbeg + t;
        if (node < n) {
            rowptr[node] = ebeg + ex;
            dinv[node] = rsqrtf((float)v + 1.0f);  // +1 = self-loop
        }
        lcur[t] = ex;
    }
    __syncthreads();
    for (int e = ebeg + t; e < eend; e += 256) {
        unsigned int w = packed[e];
        int off = atomicAdd(&lcur[w >> 25], 1);
        csr[ebeg + off] = (int)(w & SRCMASK);
    }
}

// -------- dense compute --------

// hs[row] = fp16((x[row] @ W1) * dinv[row]), padded stride 64, pad zeroed
__global__ __launch_bounds__(256) void gemm1_kernel(
    const float* __restrict__ x, const float* __restrict__ W,
    const float* __restrict__ dinv, __half* __restrict__ hs, int n) {
    __shared__ float Ws[FIN * FH];
    for (int i = threadIdx.x; i < FIN * FH; i += 256) Ws[i] = W[i];
    __syncthreads();
    int row = blockIdx.x * 256 + threadIdx.x;
    if (row >= n) return;
    float a[FH];
#pragma unroll
    for (int c = 0; c < FH; c++) a[c] = 0.f;
    const float4* xr = (const float4*)(x + (size_t)row * FIN);
    for (int k4 = 0; k4 < FIN / 4; k4++) {
        float4 xv = xr[k4];
        const float* w0 = &Ws[k4 * 4 * FH];
#pragma unroll
        for (int c = 0; c < FH; c++) {
            a[c] = fmaf(xv.x, w0[c], a[c]);
            a[c] = fmaf(xv.y, w0[c + FH], a[c]);
            a[c] = fmaf(xv.z, w0[c + 2 * FH], a[c]);
            a[c] = fmaf(xv.w, w0[c + 3 * FH], a[c]);
        }
    }
    float dv = dinv[row];
    __half2* hp = (__half2*)(hs + ((size_t)row << 6));
#pragma unroll
    for (int c = 0; c < HSTRIDE / 2; c++) {
        float lo = (2 * c     < FH) ? a[2 * c] * dv     : 0.f;
        float hi = (2 * c + 1 < FH) ? a[2 * c + 1] * dv : 0.f;
        hp[c] = __floats2half2_rn(lo, hi);
    }
}

// hs[row] = fp16((h1[row] @ W2) * dinv[row]); h1 = d_out (fp32) from gather1
__global__ __launch_bounds__(256) void gemm2_kernel(
    const float* __restrict__ h1, const float* __restrict__ W,
    const float* __restrict__ dinv, __half* __restrict__ hs, int n) {
    __shared__ float Ws[FH * FH];
    for (int i = threadIdx.x; i < FH * FH; i += 256) Ws[i] = W[i];
    __syncthreads();
    int row = blockIdx.x * 256 + threadIdx.x;
    if (row >= n) return;
    const float* xp = h1 + (size_t)row * FH;
    float xr[FH];
#pragma unroll
    for (int k = 0; k < FH; k++) xr[k] = xp[k];
    float a[FH];
#pragma unroll
    for (int c = 0; c < FH; c++) a[c] = 0.f;
    for (int k = 0; k < FH; k++) {
        float xv = xr[k];
        const float* w = &Ws[k * FH];
#pragma unroll
        for (int c = 0; c < FH; c++) a[c] = fmaf(xv, w[c], a[c]);
    }
    float dv = dinv[row];
    __half2* hp = (__half2*)(hs + ((size_t)row << 6));
#pragma unroll
    for (int c = 0; c < HSTRIDE / 2; c++) {
        float lo = (2 * c     < FH) ? a[2 * c] * dv     : 0.f;
        float hi = (2 * c + 1 < FH) ? a[2 * c + 1] * dv : 0.f;
        hp[c] = __floats2half2_rn(lo, hi);
    }
}

// one wave per dst row: acc = hs[self] + sum over in-edges hs[src] (fp16 msgs,
// fp32 accumulate); out = relu?(dinv*acc + b)
__global__ __launch_bounds__(256) void gather_kernel(
    const __half* __restrict__ hs, const int* __restrict__ rowptr,
    const int* __restrict__ csr, const float* __restrict__ dinv,
    const float* __restrict__ b, float* __restrict__ out, int n, int do_relu) {
    int wid = blockIdx.x * 4 + (threadIdx.x >> 6);
    int lane = threadIdx.x & 63;
    if (wid >= n) return;
    int beg = rowptr[wid];
    int end = rowptr[wid + 1];
    float acc = __half2float(hs[((size_t)wid << 6) + lane]);  // self-loop term
    for (int base = beg; base < end; base += 64) {
        int rem = end - base;
        int idx = (lane < rem) ? csr[base + lane] : 0;
        int cnt = rem < 64 ? rem : 64;
        for (int j = 0; j < cnt; j++) {
            int s = __shfl(idx, j);
            acc += __half2float(hs[((size_t)s << 6) + lane]);
        }
    }
    if (lane < FH) {
        float v = fmaf(dinv[wid], acc, b[lane]);
        if (do_relu) v = fmaxf(v, 0.f);
        out[(size_t)wid * FH + lane] = v;
    }
}

extern "C" void kernel_launch(void* const* d_in, const int* in_sizes, int n_in,
                              void* d_out, int out_size, void* d_ws, size_t ws_size,
                              hipStream_t stream) {
    const float* x  = (const float*)d_in[0];
    const float* W1 = (const float*)d_in[1];
    const float* b1 = (const float*)d_in[2];
    const float* W2 = (const float*)d_in[3];
    const float* b2 = (const float*)d_in[4];
    const int*   ei = (const int*)d_in[5];

    int n = in_sizes[0] / FIN;   // 100000
    int E = in_sizes[5] / 2;     // 1600000
    const int* src = ei;
    const int* dst = ei + E;
    int NB = (n + BSIZE - 1) >> BSHIFT;   // 782

    char* ws = (char*)d_ws;
    size_t off = 0;
    auto alloc = [&](size_t bytes) {
        void* p = ws + off;
        off = (off + bytes + 511) & ~(size_t)511;
        return p;
    };
    int*          bhist   = (int*)alloc((size_t)MAXNB * 4);
    int*          bofs    = (int*)alloc((size_t)(MAXNB + 1) * 4);
    int*          gcursor = (int*)alloc((size_t)MAXNB * 4);
    int*          rowptr  = (int*)alloc((size_t)(n + 1) * 4);
    float*        dinv    = (float*)alloc((size_t)n * 4);
    unsigned int* packed  = (unsigned int*)alloc((size_t)E * 4);
    int*          csr     = (int*)alloc((size_t)E * 4);
    __half*       hs      = (__half*)alloc((size_t)n * HSTRIDE * 2);
    float*        out     = (float*)d_out;

    hipMemsetAsync(bhist, 0, (size_t)NB * 4, stream);

    bhist_kernel<<<256, 256, 0, stream>>>(dst, E, bhist, NB);
    bscan_kernel<<<1, 1024, 0, stream>>>(bhist, bofs, gcursor, rowptr, NB, n, E);
    int pChunks = (E + PCHUNK - 1) / PCHUNK;   // 196
    partition_kernel<<<pChunks, 256, 0, stream>>>(src, dst, gcursor, packed, E, NB);
    bucket_build_kernel<<<NB, 256, 0, stream>>>(packed, bofs, rowptr, dinv, csr, n);

    int rowBlocks = (n + 255) / 256;
    int gatherBlocks = (n + 3) / 4;   // 4 waves/block, 1 wave/row

    gemm1_kernel<<<rowBlocks, 256, 0, stream>>>(x, W1, dinv, hs, n);
    gather_kernel<<<gatherBlocks, 256, 0, stream>>>(hs, rowptr, csr, dinv, b1, out, n, 1);
    gemm2_kernel<<<rowBlocks, 256, 0, stream>>>(out, W2, dinv, hs, n);
    gather_kernel<<<gatherBlocks, 256, 0, stream>>>(hs, rowptr, csr, dinv, b2, out, n, 0);
}

// Round 6
// 319.539 us; speedup vs baseline: 3.2885x; 1.3226x over previous
//
#include <hip/hip_runtime.h>
#include <hip/hip_fp16.h>

#define FIN 128
#define FH 50
#define HSTRIDE 64
#define MAXNB 1024        // supports n <= 131072 with 128-node buckets
#define BSHIFT 7
#define BSIZE 128
#define PCHUNK 8192       // edges per partition workgroup
#define SRCMASK 0x01FFFFFFu

// -------- CSR build: bucketed two-level counting sort --------

// per-WG LDS histogram of dst buckets -> global bhist
__global__ __launch_bounds__(256) void bhist_kernel(const int* __restrict__ dst, int E,
                                                    int* __restrict__ bhist, int NB) {
    __shared__ int h[MAXNB];
    int t = threadIdx.x;
    for (int i = t; i < NB; i += 256) h[i] = 0;
    __syncthreads();
    for (int e = blockIdx.x * 256 + t; e < E; e += gridDim.x * 256)
        atomicAdd(&h[dst[e] >> BSHIFT], 1);
    __syncthreads();
    for (int i = t; i < NB; i += 256) { int c = h[i]; if (c) atomicAdd(&bhist[i], c); }
}

// exclusive scan of bucket counts (NB <= 1024); also init gcursor, rowptr[n]
__global__ __launch_bounds__(1024) void bscan_kernel(const int* __restrict__ bhist,
                                                     int* __restrict__ bofs,
                                                     int* __restrict__ gcursor,
                                                     int* __restrict__ rowptr,
                                                     int NB, int n, int E) {
    __shared__ int tmp[1024];
    int t = threadIdx.x;
    int v = (t < NB) ? bhist[t] : 0;
    tmp[t] = v;
    __syncthreads();
    for (int off = 1; off < 1024; off <<= 1) {
        int add = (t >= off) ? tmp[t - off] : 0;
        __syncthreads();
        tmp[t] += add;
        __syncthreads();
    }
    if (t < NB) { int e = tmp[t] - v; bofs[t] = e; gcursor[t] = e; }
    if (t == 0) { bofs[NB] = E; rowptr[n] = E; }
}

// partition edges into bucket-contiguous 'packed' array: word = (dlocal<<25)|src
__global__ __launch_bounds__(256) void partition_kernel(const int* __restrict__ src,
                                                        const int* __restrict__ dst,
                                                        int* __restrict__ gcursor,
                                                        unsigned int* __restrict__ packed,
                                                        int E, int NB) {
    __shared__ int hist[MAXNB];   // phase1: counts; phase3: local cursor
    __shared__ int wbase[MAXNB];
    int t = threadIdx.x;
    int base = blockIdx.x * PCHUNK;
    for (int i = t; i < NB; i += 256) hist[i] = 0;
    __syncthreads();
#pragma unroll 4
    for (int i = 0; i < PCHUNK / 256; i++) {
        int e = base + t + i * 256;
        if (e < E) atomicAdd(&hist[dst[e] >> BSHIFT], 1);
    }
    __syncthreads();
    for (int i = t; i < NB; i += 256) {
        int c = hist[i];
        wbase[i] = c ? atomicAdd(&gcursor[i], c) : 0;
        hist[i] = 0;   // becomes local cursor
    }
    __syncthreads();
#pragma unroll 4
    for (int i = 0; i < PCHUNK / 256; i++) {
        int e = base + t + i * 256;
        if (e < E) {
            unsigned int s = (unsigned int)src[e];
            int d = dst[e];
            int b = d >> BSHIFT;
            int off = atomicAdd(&hist[b], 1);
            packed[wbase[b] + off] = ((unsigned int)(d & (BSIZE - 1)) << 25) | s;
        }
    }
}

// one WG per bucket: local degree hist -> scan -> rowptr/dinv -> csr fill
__global__ __launch_bounds__(256) void bucket_build_kernel(const unsigned int* __restrict__ packed,
                                                           const int* __restrict__ bofs,
                                                           int* __restrict__ rowptr,
                                                           float* __restrict__ dinv,
                                                           int* __restrict__ csr, int n) {
    __shared__ int degl[BSIZE];
    __shared__ int excl[BSIZE];
    __shared__ int lcur[BSIZE];
    int b = blockIdx.x;
    int t = threadIdx.x;
    int nbeg = b << BSHIFT;
    int ebeg = bofs[b], eend = bofs[b + 1];
    if (t < BSIZE) degl[t] = 0;
    __syncthreads();
    for (int e = ebeg + t; e < eend; e += 256)
        atomicAdd(&degl[packed[e] >> 25], 1);
    __syncthreads();
    int v = (t < BSIZE) ? degl[t] : 0;
    if (t < BSIZE) excl[t] = v;
    __syncthreads();
    for (int off = 1; off < BSIZE; off <<= 1) {
        int add = (t >= off && t < BSIZE) ? excl[t - off] : 0;
        __syncthreads();
        if (t < BSIZE) excl[t] += add;
        __syncthreads();
    }
    if (t < BSIZE) {
        int ex = excl[t] - v;
        int node = nbeg + t;
        if (node < n) {
            rowptr[node] = ebeg + ex;
            dinv[node] = rsqrtf((float)v + 1.0f);  // +1 = self-loop
        }
        lcur[t] = ex;
    }
    __syncthreads();
    for (int e = ebeg + t; e < eend; e += 256) {
        unsigned int w = packed[e];
        int off = atomicAdd(&lcur[w >> 25], 1);
        csr[ebeg + off] = (int)(w & SRCMASK);
    }
}

// -------- dense compute --------

// hs[row] = fp16((x[row] @ W1) * dinv[row]), padded stride 64, pad zeroed.
// Also zeroes sentinel row n (used by gather's branchless unroll).
__global__ __launch_bounds__(256) void gemm1_kernel(
    const float* __restrict__ x, const float* __restrict__ W,
    const float* __restrict__ dinv, __half* __restrict__ hs, int n) {
    __shared__ float Ws[FIN * FH];
    for (int i = threadIdx.x; i < FIN * FH; i += 256) Ws[i] = W[i];
    if (blockIdx.x == 0 && threadIdx.x < HSTRIDE)
        hs[((size_t)n << 6) + threadIdx.x] = __float2half(0.f);   // sentinel row
    __syncthreads();
    int row = blockIdx.x * 256 + threadIdx.x;
    if (row >= n) return;
    float a[FH];
#pragma unroll
    for (int c = 0; c < FH; c++) a[c] = 0.f;
    const float4* xr = (const float4*)(x + (size_t)row * FIN);
    for (int k4 = 0; k4 < FIN / 4; k4++) {
        float4 xv = xr[k4];
        const float* w0 = &Ws[k4 * 4 * FH];
#pragma unroll
        for (int c = 0; c < FH; c++) {
            a[c] = fmaf(xv.x, w0[c], a[c]);
            a[c] = fmaf(xv.y, w0[c + FH], a[c]);
            a[c] = fmaf(xv.z, w0[c + 2 * FH], a[c]);
            a[c] = fmaf(xv.w, w0[c + 3 * FH], a[c]);
        }
    }
    float dv = dinv[row];
    __half2* hp = (__half2*)(hs + ((size_t)row << 6));
#pragma unroll
    for (int c = 0; c < HSTRIDE / 2; c++) {
        float lo = (2 * c     < FH) ? a[2 * c] * dv     : 0.f;
        float hi = (2 * c + 1 < FH) ? a[2 * c + 1] * dv : 0.f;
        hp[c] = __floats2half2_rn(lo, hi);
    }
}

// hs[row] = fp16((h1[row] @ W2) * dinv[row]); h1 = d_out (fp32) from gather1
__global__ __launch_bounds__(256) void gemm2_kernel(
    const float* __restrict__ h1, const float* __restrict__ W,
    const float* __restrict__ dinv, __half* __restrict__ hs, int n) {
    __shared__ float Ws[FH * FH];
    for (int i = threadIdx.x; i < FH * FH; i += 256) Ws[i] = W[i];
    __syncthreads();
    int row = blockIdx.x * 256 + threadIdx.x;
    if (row >= n) return;
    const float* xp = h1 + (size_t)row * FH;
    float xr[FH];
#pragma unroll
    for (int k = 0; k < FH; k++) xr[k] = xp[k];
    float a[FH];
#pragma unroll
    for (int c = 0; c < FH; c++) a[c] = 0.f;
    for (int k = 0; k < FH; k++) {
        float xv = xr[k];
        const float* w = &Ws[k * FH];
#pragma unroll
        for (int c = 0; c < FH; c++) a[c] = fmaf(xv, w[c], a[c]);
    }
    float dv = dinv[row];
    __half2* hp = (__half2*)(hs + ((size_t)row << 6));
#pragma unroll
    for (int c = 0; c < HSTRIDE / 2; c++) {
        float lo = (2 * c     < FH) ? a[2 * c] * dv     : 0.f;
        float hi = (2 * c + 1 < FH) ? a[2 * c + 1] * dv : 0.f;
        hp[c] = __floats2half2_rn(lo, hi);
    }
}

// one wave per dst row (R4-proven layout): acc = hs[self] + sum hs[csr[...]].
// Edge loop unrolled x8, branchless: lanes >= rem hold sentinel index n whose
// hs row is all zeros, so shuffled indices past cnt contribute 0. 8 gather
// loads in flight per vmcnt wait. fp32 accumulate.
__global__ __launch_bounds__(256) void gather_kernel(
    const __half* __restrict__ hs, const int* __restrict__ rowptr,
    const int* __restrict__ csr, const float* __restrict__ dinv,
    const float* __restrict__ b, float* __restrict__ out, int n, int do_relu) {
    int wid = blockIdx.x * 4 + (threadIdx.x >> 6);
    int lane = threadIdx.x & 63;
    if (wid >= n) return;
    int beg = rowptr[wid];
    int end = rowptr[wid + 1];
    float acc = __half2float(hs[((size_t)wid << 6) + lane]);  // self-loop term
    for (int base = beg; base < end; base += 64) {
        int rem = end - base;
        int idx = (lane < rem) ? csr[base + lane] : n;   // n = zero sentinel
        int cnt = rem < 64 ? rem : 64;
        for (int j = 0; j < cnt; j += 8) {               // j <= 56, j+7 <= 63
            int s0 = __shfl(idx, j);
            int s1 = __shfl(idx, j + 1);
            int s2 = __shfl(idx, j + 2);
            int s3 = __shfl(idx, j + 3);
            int s4 = __shfl(idx, j + 4);
            int s5 = __shfl(idx, j + 5);
            int s6 = __shfl(idx, j + 6);
            int s7 = __shfl(idx, j + 7);
            float v0 = __half2float(hs[((size_t)s0 << 6) + lane]);
            float v1 = __half2float(hs[((size_t)s1 << 6) + lane]);
            float v2 = __half2float(hs[((size_t)s2 << 6) + lane]);
            float v3 = __half2float(hs[((size_t)s3 << 6) + lane]);
            float v4 = __half2float(hs[((size_t)s4 << 6) + lane]);
            float v5 = __half2float(hs[((size_t)s5 << 6) + lane]);
            float v6 = __half2float(hs[((size_t)s6 << 6) + lane]);
            float v7 = __half2float(hs[((size_t)s7 << 6) + lane]);
            acc += ((v0 + v1) + (v2 + v3)) + ((v4 + v5) + (v6 + v7));
        }
    }
    if (lane < FH) {
        float v = fmaf(dinv[wid], acc, b[lane]);
        if (do_relu) v = fmaxf(v, 0.f);
        out[(size_t)wid * FH + lane] = v;
    }
}

extern "C" void kernel_launch(void* const* d_in, const int* in_sizes, int n_in,
                              void* d_out, int out_size, void* d_ws, size_t ws_size,
                              hipStream_t stream) {
    const float* x  = (const float*)d_in[0];
    const float* W1 = (const float*)d_in[1];
    const float* b1 = (const float*)d_in[2];
    const float* W2 = (const float*)d_in[3];
    const float* b2 = (const float*)d_in[4];
    const int*   ei = (const int*)d_in[5];

    int n = in_sizes[0] / FIN;   // 100000
    int E = in_sizes[5] / 2;     // 1600000
    const int* src = ei;
    const int* dst = ei + E;
    int NB = (n + BSIZE - 1) >> BSHIFT;   // 782

    char* ws = (char*)d_ws;
    size_t off = 0;
    auto alloc = [&](size_t bytes) {
        void* p = ws + off;
        off = (off + bytes + 511) & ~(size_t)511;
        return p;
    };
    int*          bhist   = (int*)alloc((size_t)MAXNB * 4);
    int*          bofs    = (int*)alloc((size_t)(MAXNB + 1) * 4);
    int*          gcursor = (int*)alloc((size_t)MAXNB * 4);
    int*          rowptr  = (int*)alloc((size_t)(n + 1) * 4);
    float*        dinv    = (float*)alloc((size_t)n * 4);
    unsigned int* packed  = (unsigned int*)alloc((size_t)E * 4);
    int*          csr     = (int*)alloc((size_t)E * 4);
    __half*       hs      = (__half*)alloc((size_t)(n + 1) * HSTRIDE * 2); // +1 sentinel
    float*        out     = (float*)d_out;

    hipMemsetAsync(bhist, 0, (size_t)NB * 4, stream);

    bhist_kernel<<<256, 256, 0, stream>>>(dst, E, bhist, NB);
    bscan_kernel<<<1, 1024, 0, stream>>>(bhist, bofs, gcursor, rowptr, NB, n, E);
    int pChunks = (E + PCHUNK - 1) / PCHUNK;   // 196
    partition_kernel<<<pChunks, 256, 0, stream>>>(src, dst, gcursor, packed, E, NB);
    bucket_build_kernel<<<NB, 256, 0, stream>>>(packed, bofs, rowptr, dinv, csr, n);

    int rowBlocks = (n + 255) / 256;
    int gatherBlocks = (n + 3) / 4;   // 4 waves/block, 1 wave/row

    gemm1_kernel<<<rowBlocks, 256, 0, stream>>>(x, W1, dinv, hs, n);
    gather_kernel<<<gatherBlocks, 256, 0, stream>>>(hs, rowptr, csr, dinv, b1, out, n, 1);
    gemm2_kernel<<<rowBlocks, 256, 0, stream>>>(out, W2, dinv, hs, n);
    gather_kernel<<<gatherBlocks, 256, 0, stream>>>(hs, rowptr, csr, dinv, b2, out, n, 0);
}